// Round 1
// 838.966 us; speedup vs baseline: 1.0037x; 1.0037x over previous
//
#include <hip/hip_runtime.h>
#include <cstddef>
#include <cstdint>

#define GG 4
#define SS 2048
#define MM 1024
#define EE 64
// tokens = GG*SS = 8192, capacity C = 160 (computed in kernel_launch)

// ---------------------------------------------------------------------------
// Kernel A: gating — logits (token x expert dot products), softmax, argmax,
// gate value, and per-(g,e) softmax-mass accumulation (aux-loss proxy).
// Layout: lane = expert (64 lanes == 64 experts), each wave owns 4 tokens,
// 4 waves per block => 16 tokens/block, 512 blocks.
// ---------------------------------------------------------------------------
__global__ __launch_bounds__(256) void gating_kernel(
    const float* __restrict__ x,      // [G*S, M]
    const float* __restrict__ W,      // [M, E]
    int*   __restrict__ expert_out,   // [G*S]
    float* __restrict__ gate_out,     // [G*S]
    float* __restrict__ proxy)        // [G*E], pre-zeroed
{
    __shared__ float lds_proxy[EE];
    const int tid  = threadIdx.x;
    const int wave = tid >> 6;
    const int lane = tid & 63;        // = expert index for this lane

    if (tid < EE) lds_proxy[tid] = 0.0f;
    __syncthreads();

    const int t0 = blockIdx.x * 16 + wave * 4;      // first of 4 tokens
    const float* xr = x + (size_t)t0 * MM;

    float acc[4][4];
#pragma unroll
    for (int i = 0; i < 4; ++i)
#pragma unroll
        for (int j = 0; j < 4; ++j) acc[i][j] = 0.0f;

    for (int m = 0; m < MM; m += 4) {
        const float w0 = W[(m + 0) * EE + lane];
        const float w1 = W[(m + 1) * EE + lane];
        const float w2 = W[(m + 2) * EE + lane];
        const float w3 = W[(m + 3) * EE + lane];
#pragma unroll
        for (int i = 0; i < 4; ++i) {
            const float4 xv = *reinterpret_cast<const float4*>(xr + (size_t)i * MM + m);
            acc[i][0] = fmaf(xv.x, w0, acc[i][0]);
            acc[i][1] = fmaf(xv.y, w1, acc[i][1]);
            acc[i][2] = fmaf(xv.z, w2, acc[i][2]);
            acc[i][3] = fmaf(xv.w, w3, acc[i][3]);
        }
    }

    const int g = blockIdx.x / (SS / 16);   // 16 tokens/block, 2048 tokens/group

#pragma unroll
    for (int i = 0; i < 4; ++i) {
        // combine stripes in fp64 (deterministic, high accuracy for argmax)
        double logit = ((double)acc[i][0] + (double)acc[i][1]) +
                       ((double)acc[i][2] + (double)acc[i][3]);

        // argmax over lanes, first-index tie-break (np.argmax semantics)
        double v = logit;
        int idx = lane;
        for (int off = 32; off; off >>= 1) {
            double ov = __shfl_xor(v, off);
            int    oi = __shfl_xor(idx, off);
            if (ov > v || (ov == v && oi < idx)) { v = ov; idx = oi; }
        }

        // softmax denominator (shifted by max)
        float p  = __expf((float)(logit - v));
        float ps = p;
        for (int off = 32; off; off >>= 1) ps += __shfl_xor(ps, off);
        float inv = 1.0f / ps;            // = softmax value at the argmax

        atomicAdd(&lds_proxy[lane], p * inv);   // this lane's expert prob

        if (lane == 0) {
            expert_out[t0 + i] = idx;
            gate_out[t0 + i]   = inv;
        }
    }

    __syncthreads();
    if (tid < EE) atomicAdd(&proxy[g * EE + tid], lds_proxy[tid]);
}

// ---------------------------------------------------------------------------
// Kernel B: exclusive cumsum over the sequence axis per (g,e) via ballot scan,
// fused with the scatter into combine_tensor / dispatch_mask (the wave that
// computes a token's position writes its output entry directly).
// One wave per (g,e) pair: 256 waves -> 64 blocks x 256 threads.
// ---------------------------------------------------------------------------
__global__ __launch_bounds__(256) void scan_scatter_kernel(
    const int*   __restrict__ expert,  // [G*S]
    const float* __restrict__ gate,    // [G*S]
    int*   __restrict__ count,         // [G*E]
    float* __restrict__ out,           // combine base; dispatch at out + N
    int C, size_t N)
{
    const int wid  = (int)((blockIdx.x * blockDim.x + threadIdx.x) >> 6); // 0..255
    const int lane = threadIdx.x & 63;
    const int g = wid >> 6;
    const int e = wid & 63;
    const int* ex = expert + g * SS;

    int running = 0;
    for (int s0 = 0; s0 < SS; s0 += 64) {
        const int myex = ex[s0 + lane];
        const unsigned long long m = __ballot(myex == e);
        if (myex == e) {
            const int p = running + __popcll(m & ((1ull << lane) - 1ull));
            if (p < C) {
                const int t = g * SS + s0 + lane;
                const size_t off = ((size_t)t * EE + e) * (size_t)C + (size_t)p;
                out[off]     = gate[t];
                out[N + off] = 1.0f;
            }
        }
        running += __popcll(m);
    }
    if (lane == 0) count[g * EE + e] = running;
}

// ---------------------------------------------------------------------------
// Kernel C: aux load-balancing loss (scalar).
// ---------------------------------------------------------------------------
__global__ __launch_bounds__(256) void aux_kernel(
    const float* __restrict__ proxy,  // [G*E] sum of probs over s
    const int*   __restrict__ count,  // [G*E] token counts
    float* __restrict__ out_aux)
{
    __shared__ float red[4];
    const int i = threadIdx.x;        // 0..255 -> (g,e)
    const float denom = (float)SS * (1.0f + 1e-6f);
    float term = (proxy[i] / denom) * ((float)count[i] / denom);
    for (int off = 32; off; off >>= 1) term += __shfl_xor(term, off);
    if ((i & 63) == 0) red[i >> 6] = term;
    __syncthreads();
    if (i == 0) {
        float tot = (red[0] + red[1]) + (red[2] + red[3]);
        *out_aux = tot / (float)(GG * EE) * ((float)(EE * EE) * 0.01f);
    }
}

// ---------------------------------------------------------------------------
extern "C" void kernel_launch(void* const* d_in, const int* in_sizes, int n_in,
                              void* d_out, int out_size, void* d_ws, size_t ws_size,
                              hipStream_t stream) {
    const float* x = (const float*)d_in[0];
    const float* W = (const float*)d_in[1];
    float* out = (float*)d_out;

    // capacity: int(tokens/E * 1.25) with ceil-if-frac, min 4  -> 160 here
    const int tokens = GG * SS;
    const double cap = (double)tokens / (double)EE * 1.25;
    int C = (int)cap;
    if (cap > (double)C) C += 1;
    if (C < 4) C = 4;
    const size_t N = (size_t)tokens * EE * (size_t)C;   // G*S*E*C

    // workspace layout
    float* proxy  = (float*)d_ws;                // G*E floats (needs zeroing)
    int*   expert = (int*)(proxy + GG * EE);     // G*S ints
    float* gate   = (float*)(expert + tokens);   // G*S floats
    int*   count  = (int*)(gate + tokens);       // G*E ints

    // Zero EXACTLY the bytes the op needs: combine (N) + dispatch (N) floats.
    // (The aux scalar at out + 2N is unconditionally written by aux_kernel.)
    // Previous version zeroed out_size*sizeof(float) = 4x this -> ~320us waste.
    hipMemsetAsync(d_out, 0, (size_t)2 * N * sizeof(float), stream);
    hipMemsetAsync(proxy, 0, (size_t)(GG * EE) * sizeof(float), stream);

    gating_kernel<<<tokens / 16, 256, 0, stream>>>(x, W, expert, gate, proxy);
    scan_scatter_kernel<<<(GG * EE) / 4, 256, 0, stream>>>(expert, gate, count, out, C, N);
    aux_kernel<<<1, 256, 0, stream>>>(proxy, count, out + 2 * N);
}